// Round 4
// baseline (445.564 us; speedup 1.0000x reference)
//
#include <hip/hip_runtime.h>
#include <stdint.h>

#define M_TOT 2048   // B*C
#define N_TOT 16384  // B*F
#define K_TOT 512    // D

typedef _Float16 f16x8 __attribute__((ext_vector_type(8)));
typedef float f32x4 __attribute__((ext_vector_type(4)));

#define AS1 __attribute__((address_space(1)))
#define AS3 __attribute__((address_space(3)))

__device__ __forceinline__ void ld_lds16(const void* g, void* l) {
    __builtin_amdgcn_global_load_lds((const AS1 void*)g, (AS3 void*)l, 16, 0, 0);
}

// ---------------- Kernel 1: norms + f16 hi/lo split planes ----------------
__device__ __forceinline__ void split4(float x0, float x1, float x2, float x3,
                                       uint2* hs, uint2* ls) {
    union U { _Float16 h[4]; uint2 u; } H, L;
    _Float16 h0 = (_Float16)x0; H.h[0] = h0; L.h[0] = (_Float16)(x0 - (float)h0);
    _Float16 h1 = (_Float16)x1; H.h[1] = h1; L.h[1] = (_Float16)(x1 - (float)h1);
    _Float16 h2 = (_Float16)x2; H.h[2] = h2; L.h[2] = (_Float16)(x2 - (float)h2);
    _Float16 h3 = (_Float16)x3; H.h[3] = h3; L.h[3] = (_Float16)(x3 - (float)h3);
    *hs = H.u; *ls = L.u;
}

__global__ __launch_bounds__(256) void norm_split_kernel(
    const float* __restrict__ c_feats, const float* __restrict__ f_feats,
    _Float16* __restrict__ Ah, _Float16* __restrict__ Al,
    _Float16* __restrict__ Bh, _Float16* __restrict__ Bl,
    float* __restrict__ normf)
{
    int wave = blockIdx.x * 4 + (threadIdx.x >> 6);
    int lane = threadIdx.x & 63;
    if (wave < 2048) {
        const float* row = c_feats + (size_t)wave * K_TOT;
        float4 v0 = ((const float4*)row)[lane];
        float4 v1 = ((const float4*)row)[lane + 64];
        double ss = (double)v0.x * v0.x + (double)v0.y * v0.y +
                    (double)v0.z * v0.z + (double)v0.w * v0.w +
                    (double)v1.x * v1.x + (double)v1.y * v1.y +
                    (double)v1.z * v1.z + (double)v1.w * v1.w;
        #pragma unroll
        for (int off = 32; off; off >>= 1) ss += __shfl_down(ss, off);
        double tot = __shfl(ss, 0);
        float nrm = sqrtf((float)tot);
        float a0 = v0.x / nrm, a1 = v0.y / nrm, a2 = v0.z / nrm, a3 = v0.w / nrm;
        float b0 = v1.x / nrm, b1 = v1.y / nrm, b2 = v1.z / nrm, b3 = v1.w / nrm;
        uint2 h, l;
        split4(a0, a1, a2, a3, &h, &l);
        ((uint2*)(Ah + (size_t)wave * K_TOT))[lane] = h;
        ((uint2*)(Al + (size_t)wave * K_TOT))[lane] = l;
        split4(b0, b1, b2, b3, &h, &l);
        ((uint2*)(Ah + (size_t)wave * K_TOT))[lane + 64] = h;
        ((uint2*)(Al + (size_t)wave * K_TOT))[lane + 64] = l;
    } else if (wave < 18432) {
        int fr = wave - 2048;
        const float* row = f_feats + (size_t)fr * K_TOT;
        float4 v0 = ((const float4*)row)[lane];
        float4 v1 = ((const float4*)row)[lane + 64];
        double ss = (double)v0.x * v0.x + (double)v0.y * v0.y +
                    (double)v0.z * v0.z + (double)v0.w * v0.w +
                    (double)v1.x * v1.x + (double)v1.y * v1.y +
                    (double)v1.z * v1.z + (double)v1.w * v1.w;
        #pragma unroll
        for (int off = 32; off; off >>= 1) ss += __shfl_down(ss, off);
        if (lane == 0) normf[fr] = sqrtf((float)ss);
        uint2 h, l;
        split4(v0.x, v0.y, v0.z, v0.w, &h, &l);
        ((uint2*)(Bh + (size_t)fr * K_TOT))[lane] = h;
        ((uint2*)(Bl + (size_t)fr * K_TOT))[lane] = l;
        split4(v1.x, v1.y, v1.z, v1.w, &h, &l);
        ((uint2*)(Bh + (size_t)fr * K_TOT))[lane + 64] = h;
        ((uint2*)(Bl + (size_t)fr * K_TOT))[lane + 64] = l;
    }
}

// ---------------- Kernel 2: fused split-f16 MFMA GEMM + DTW ----------------
// Block computes 128x128 C-tile = 8 complete problems (8 row-blocks x n-block nn).
// S never touches global: LDS-staged per 4-problem batch, wavefront DP + backtrack,
// only the 0/1 mask is written to out.
#define SST 136                      // padded S row stride (floats)
#define S_BYTES (4 * 16 * SST * 4)   // 34816
#define MV_OFF S_BYTES
#define MV_STRIDE 2080
#define BND_OFF (MV_OFF + 4 * MV_STRIDE)   // 43136
#define SMEM_BYTES (BND_OFF + 4 * 16 * 4)  // 43392

__global__ __launch_bounds__(256, 2) void fused_gemm_dtw_kernel(
    const _Float16* __restrict__ Ah, const _Float16* __restrict__ Al,
    const _Float16* __restrict__ Bh, const _Float16* __restrict__ Bl,
    const float* __restrict__ normf,
    float* __restrict__ out)
{
    __shared__ __align__(16) uint8_t smem[SMEM_BYTES];
    _Float16* sAh = (_Float16*)smem;            // [128*32]
    _Float16* sAl = sAh + 4096;
    _Float16* sBh = sAl + 4096;
    _Float16* sBl = sBh + 4096;
    float* Sl = (float*)smem;                   // epilogue: [4][16][SST]
    uint8_t* mvl = smem + MV_OFF;               // [4][MV_STRIDE]
    int* bnd = (int*)(smem + BND_OFF);          // [4][16]

    const int t = threadIdx.x;
    const int w = t >> 6, lane = t & 63;
    const int gm0 = blockIdx.y * 128, gn0 = blockIdx.x * 128;
    const int wm = (w & 1) * 64, wn = (w >> 1) * 64;
    const int fr = lane & 15, fq = lane >> 4;

    f32x4 acc[4][4] = {};
    const int l0 = w * 128 + lane;

    for (int k0 = 0; k0 < K_TOT; k0 += 32) {
        #pragma unroll
        for (int c = 0; c < 2; ++c) {
            int l = l0 + c * 64;
            int row = l >> 2, kq = l & 3;
            size_t goffA = (size_t)(gm0 + row) * K_TOT + k0 + kq * 8;
            size_t goffB = (size_t)(gn0 + row) * K_TOT + k0 + kq * 8;
            ld_lds16(Ah + goffA, sAh + (size_t)l * 8);
            ld_lds16(Al + goffA, sAl + (size_t)l * 8);
            ld_lds16(Bh + goffB, sBh + (size_t)l * 8);
            ld_lds16(Bl + goffB, sBl + (size_t)l * 8);
        }
        __syncthreads();

        f16x8 fah[4], fal[4], fbh[4], fbl[4];
        #pragma unroll
        for (int x = 0; x < 4; ++x) {
            int ar = (wm + x * 16 + fr) * 32 + fq * 8;
            int br = (wn + x * 16 + fr) * 32 + fq * 8;
            fah[x] = *(const f16x8*)(sAh + ar);
            fal[x] = *(const f16x8*)(sAl + ar);
            fbh[x] = *(const f16x8*)(sBh + br);
            fbl[x] = *(const f16x8*)(sBl + br);
        }
        #pragma unroll
        for (int mi = 0; mi < 4; ++mi)
            #pragma unroll
            for (int ni = 0; ni < 4; ++ni) {
                acc[mi][ni] = __builtin_amdgcn_mfma_f32_16x16x32_f16(fah[mi], fbl[ni], acc[mi][ni], 0, 0, 0);
                acc[mi][ni] = __builtin_amdgcn_mfma_f32_16x16x32_f16(fal[mi], fbh[ni], acc[mi][ni], 0, 0, 0);
                acc[mi][ni] = __builtin_amdgcn_mfma_f32_16x16x32_f16(fah[mi], fbh[ni], acc[mi][ni], 0, 0, 0);
            }
        __syncthreads();
    }

    // ---------------- fused DTW epilogue ----------------
    const int nn = blockIdx.x;
    const double NEG = -1e300;

    for (int b = 0; b < 2; ++b) {
        __syncthreads();
        // stage S for this batch's 4 problems (row-blocks lb = b*4 + mi)
        if ((w & 1) == b) {
            #pragma unroll
            for (int ni = 0; ni < 4; ++ni) {
                int col = wn + ni * 16 + fr;
                bool cn = (col < 16);
                float nf = cn ? normf[gn0 + col] : 1.f;
                #pragma unroll
                for (int mi = 0; mi < 4; ++mi) {
                    #pragma unroll
                    for (int rp = 0; rp < 4; ++rp) {
                        int rr = fq * 4 + rp;        // row within problem
                        float v = acc[mi][ni][rp];
                        if (cn && col <= rr) v /= nf;
                        Sl[(mi * 16 + rr) * SST + col] = v;
                    }
                }
            }
        }
        __syncthreads();

        // DP: wave w runs problem region mi = w (lanes 0-15 live, replicas masked)
        const float* Srow = Sl + (w * 16 + fr) * SST;
        uint8_t* mymv = mvl + w * MV_STRIDE;
        double Dp = NEG, Dp2 = NEG;
        for (int st = 0; st < 143; ++st) {
            int j = st - fr;
            bool act = (j >= 0) && (j < 128);
            int jc = act ? j : 0;
            float sv = Srow[jc];
            double up = __shfl_up(Dp, 1);
            double dg = __shfl_up(Dp2, 1);
            double lf = Dp;
            if (fr == 0) up = NEG;
            if (j == 0) {
                lf = NEG;
                dg = (fr == 0) ? 0.0 : NEG;
            } else if (fr == 0) {
                dg = NEG;
            }
            int m = (up >= lf && up >= dg) ? 0 : ((lf >= dg) ? 1 : 2);
            double Dc = fmax(up, fmax(lf, dg)) + (double)sv;
            if (act && fq == 0) mymv[j * 16 + fr] = (uint8_t)m;
            Dp2 = Dp;
            Dp = Dc;
        }
        __syncthreads();

        // backtrack: lane 0 of each wave walks its problem's move matrix
        if (lane == 0) {
            int i = 16, jj = 128, hic = 127;
            for (int it = 0; it < 160; ++it) {
                if (i <= 0) break;
                int m = mymv[(jj - 1) * 16 + (i - 1)];
                if (m == 1) { --jj; continue; }
                bnd[w * 16 + i - 1] = (jj - 1) | (hic << 8);
                if (m == 2) --jj;
                --i;
                hic = jj - 1;
            }
        }
        __syncthreads();

        // write this problem's mask: 512 float4, coalesced
        float* tb = out + (size_t)((blockIdx.y * 8 + b * 4 + w) * 128 + nn) * 2048;
        #pragma unroll
        for (int it = 0; it < 8; ++it) {
            int flat = it * 64 + lane;
            int ii = flat >> 5, c4 = flat & 31;
            int bb = bnd[w * 16 + ii];
            int lo = bb & 0xff, hi = (bb >> 8) & 0xff;
            int j0 = c4 * 4;
            float4 v;
            v.x = (j0 + 0 >= lo && j0 + 0 <= hi) ? 1.f : 0.f;
            v.y = (j0 + 1 >= lo && j0 + 1 <= hi) ? 1.f : 0.f;
            v.z = (j0 + 2 >= lo && j0 + 2 <= hi) ? 1.f : 0.f;
            v.w = (j0 + 3 >= lo && j0 + 3 <= hi) ? 1.f : 0.f;
            *(float4*)(tb + ii * 128 + j0) = v;
        }
    }
}

extern "C" void kernel_launch(void* const* d_in, const int* in_sizes, int n_in,
                              void* d_out, int out_size, void* d_ws, size_t ws_size,
                              hipStream_t stream)
{
    const float* c_feats = (const float*)d_in[0];
    const float* f_feats = (const float*)d_in[1];
    float* out = (float*)d_out;

    _Float16* Ah = (_Float16*)d_ws;
    _Float16* Al = Ah + (size_t)M_TOT * K_TOT;
    _Float16* Bh = Al + (size_t)M_TOT * K_TOT;
    _Float16* Bl = Bh + (size_t)N_TOT * K_TOT;
    float* normf = (float*)(Bl + (size_t)N_TOT * K_TOT);

    norm_split_kernel<<<4608, 256, 0, stream>>>(c_feats, f_feats, Ah, Al, Bh, Bl, normf);
    dim3 g(N_TOT / 128, M_TOT / 128);
    fused_gemm_dtw_kernel<<<g, 256, 0, stream>>>(Ah, Al, Bh, Bl, normf, out);
}

// Round 5
// 365.096 us; speedup vs baseline: 1.2204x; 1.2204x over previous
//
#include <hip/hip_runtime.h>
#include <stdint.h>

#define M_TOT 2048   // B*C
#define N_TOT 16384  // B*F
#define K_TOT 512    // D

typedef _Float16 f16x8 __attribute__((ext_vector_type(8)));
typedef float f32x4 __attribute__((ext_vector_type(4)));
typedef float f32x16 __attribute__((ext_vector_type(16)));

#define AS1 __attribute__((address_space(1)))
#define AS3 __attribute__((address_space(3)))

__device__ __forceinline__ void ld_lds16(const void* g, void* l) {
    __builtin_amdgcn_global_load_lds((const AS1 void*)g, (AS3 void*)l, 16, 0, 0);
}

// ---------------- Kernel 1: norms + f16 hi/lo split planes ----------------
__device__ __forceinline__ void split4(float x0, float x1, float x2, float x3,
                                       uint2* hs, uint2* ls) {
    union U { _Float16 h[4]; uint2 u; } H, L;
    _Float16 h0 = (_Float16)x0; H.h[0] = h0; L.h[0] = (_Float16)(x0 - (float)h0);
    _Float16 h1 = (_Float16)x1; H.h[1] = h1; L.h[1] = (_Float16)(x1 - (float)h1);
    _Float16 h2 = (_Float16)x2; H.h[2] = h2; L.h[2] = (_Float16)(x2 - (float)h2);
    _Float16 h3 = (_Float16)x3; H.h[3] = h3; L.h[3] = (_Float16)(x3 - (float)h3);
    *hs = H.u; *ls = L.u;
}

__global__ __launch_bounds__(256) void norm_split_kernel(
    const float* __restrict__ c_feats, const float* __restrict__ f_feats,
    _Float16* __restrict__ Ah, _Float16* __restrict__ Al,
    _Float16* __restrict__ Bh, _Float16* __restrict__ Bl,
    float* __restrict__ normf)
{
    int wave = blockIdx.x * 4 + (threadIdx.x >> 6);
    int lane = threadIdx.x & 63;
    if (wave < 2048) {
        const float* row = c_feats + (size_t)wave * K_TOT;
        float4 v0 = ((const float4*)row)[lane];
        float4 v1 = ((const float4*)row)[lane + 64];
        double ss = (double)v0.x * v0.x + (double)v0.y * v0.y +
                    (double)v0.z * v0.z + (double)v0.w * v0.w +
                    (double)v1.x * v1.x + (double)v1.y * v1.y +
                    (double)v1.z * v1.z + (double)v1.w * v1.w;
        #pragma unroll
        for (int off = 32; off; off >>= 1) ss += __shfl_down(ss, off);
        double tot = __shfl(ss, 0);
        float nrm = sqrtf((float)tot);
        float a0 = v0.x / nrm, a1 = v0.y / nrm, a2 = v0.z / nrm, a3 = v0.w / nrm;
        float b0 = v1.x / nrm, b1 = v1.y / nrm, b2 = v1.z / nrm, b3 = v1.w / nrm;
        uint2 h, l;
        split4(a0, a1, a2, a3, &h, &l);
        ((uint2*)(Ah + (size_t)wave * K_TOT))[lane] = h;
        ((uint2*)(Al + (size_t)wave * K_TOT))[lane] = l;
        split4(b0, b1, b2, b3, &h, &l);
        ((uint2*)(Ah + (size_t)wave * K_TOT))[lane + 64] = h;
        ((uint2*)(Al + (size_t)wave * K_TOT))[lane + 64] = l;
    } else if (wave < 18432) {
        int fr = wave - 2048;
        const float* row = f_feats + (size_t)fr * K_TOT;
        float4 v0 = ((const float4*)row)[lane];
        float4 v1 = ((const float4*)row)[lane + 64];
        double ss = (double)v0.x * v0.x + (double)v0.y * v0.y +
                    (double)v0.z * v0.z + (double)v0.w * v0.w +
                    (double)v1.x * v1.x + (double)v1.y * v1.y +
                    (double)v1.z * v1.z + (double)v1.w * v1.w;
        #pragma unroll
        for (int off = 32; off; off >>= 1) ss += __shfl_down(ss, off);
        if (lane == 0) normf[fr] = sqrtf((float)ss);
        uint2 h, l;
        split4(v0.x, v0.y, v0.z, v0.w, &h, &l);
        ((uint2*)(Bh + (size_t)fr * K_TOT))[lane] = h;
        ((uint2*)(Bl + (size_t)fr * K_TOT))[lane] = l;
        split4(v1.x, v1.y, v1.z, v1.w, &h, &l);
        ((uint2*)(Bh + (size_t)fr * K_TOT))[lane + 64] = h;
        ((uint2*)(Bl + (size_t)fr * K_TOT))[lane + 64] = l;
    }
}

// ---------------- Kernel 2: split-f16 MFMA GEMM (32x32x16), S staged into out ----------------
// Per wave: 64x64 tile = 2x2 of 32x32. A/B frag: m=lane&31, k=kh*16+(lane>>5)*8+j.
// C/D: col=lane&31, row=(reg&3)+8*(reg>>2)+4*(lane>>5)  [m74/m101-verified]
__global__ __launch_bounds__(256, 2) void mfma_gemm_kernel(
    const _Float16* __restrict__ Ah, const _Float16* __restrict__ Al,
    const _Float16* __restrict__ Bh, const _Float16* __restrict__ Bl,
    const float* __restrict__ normf,
    float* __restrict__ out)
{
    __shared__ _Float16 sAh[128 * 32];
    __shared__ _Float16 sAl[128 * 32];
    __shared__ _Float16 sBh[128 * 32];
    __shared__ _Float16 sBl[128 * 32];

    const int t = threadIdx.x;
    const int w = t >> 6, lane = t & 63;
    const int gm0 = blockIdx.y * 128, gn0 = blockIdx.x * 128;
    const int wm = (w & 1) * 64, wn = (w >> 1) * 64;
    const int m32 = lane & 31, ko8 = (lane >> 5) * 8;

    f32x16 acc[2][2] = {};
    const int l0 = w * 128 + lane;

    for (int k0 = 0; k0 < K_TOT; k0 += 32) {
        #pragma unroll
        for (int c = 0; c < 2; ++c) {
            int l = l0 + c * 64;
            int row = l >> 2, kq = l & 3;
            size_t goffA = (size_t)(gm0 + row) * K_TOT + k0 + kq * 8;
            size_t goffB = (size_t)(gn0 + row) * K_TOT + k0 + kq * 8;
            ld_lds16(Ah + goffA, sAh + (size_t)l * 8);
            ld_lds16(Al + goffA, sAl + (size_t)l * 8);
            ld_lds16(Bh + goffB, sBh + (size_t)l * 8);
            ld_lds16(Bl + goffB, sBl + (size_t)l * 8);
        }
        __syncthreads();

        #pragma unroll
        for (int kh = 0; kh < 2; ++kh) {
            f16x8 fah[2], fal[2], fbh[2], fbl[2];
            #pragma unroll
            for (int x = 0; x < 2; ++x) {
                int ar = (wm + x * 32 + m32) * 32 + kh * 16 + ko8;
                int br = (wn + x * 32 + m32) * 32 + kh * 16 + ko8;
                fah[x] = *(const f16x8*)(sAh + ar);
                fal[x] = *(const f16x8*)(sAl + ar);
                fbh[x] = *(const f16x8*)(sBh + br);
                fbl[x] = *(const f16x8*)(sBl + br);
            }
            #pragma unroll
            for (int mi = 0; mi < 2; ++mi)
                #pragma unroll
                for (int ni = 0; ni < 2; ++ni) {
                    acc[mi][ni] = __builtin_amdgcn_mfma_f32_32x32x16_f16(fah[mi], fbl[ni], acc[mi][ni], 0, 0, 0);
                    acc[mi][ni] = __builtin_amdgcn_mfma_f32_32x32x16_f16(fal[mi], fbh[ni], acc[mi][ni], 0, 0, 0);
                    acc[mi][ni] = __builtin_amdgcn_mfma_f32_32x32x16_f16(fah[mi], fbh[ni], acc[mi][ni], 0, 0, 0);
                }
        }
        __syncthreads();
    }

    const int nn = blockIdx.x;
    const int rq = 4 * (lane >> 5);
    #pragma unroll
    for (int ni = 0; ni < 2; ++ni) {
        int col = wn + ni * 32 + m32;
        bool cn = (col < 16);
        float nf = cn ? normf[gn0 + col] : 1.f;
        #pragma unroll
        for (int mi = 0; mi < 2; ++mi) {
            #pragma unroll
            for (int reg = 0; reg < 16; ++reg) {
                int r = wm + mi * 32 + (reg & 3) + 8 * (reg >> 2) + rq;
                int gm = gm0 + r;
                int mm = gm >> 4, ii = gm & 15;
                float v = acc[mi][ni][reg];
                if (cn && col <= ii) v /= nf;
                out[(((size_t)mm * 128 + nn) * 16 + ii) * 128 + col] = v;
            }
        }
    }
}

// ---------------- Kernel 3: wavefront DTW, 4 problems/wave (round-3 verified) ----------------
__global__ __launch_bounds__(256) void dtw_kernel(float* __restrict__ buf)
{
    __shared__ uint8_t mv_lds[4][4][2064];  // [wave][q][j*16+r], padded stride
    __shared__ int bounds[4][4][16];        // lo | hi<<8 per row

    const int lane = threadIdx.x & 63;
    const int w = threadIdx.x >> 6;
    const int q = lane >> 4, r = lane & 15;
    const int pbase = blockIdx.x * 16 + w * 4;
    const int p = pbase + q;
    float* tile = buf + (size_t)p * 2048;
    const float4* row4 = (const float4*)(tile + r * 128);
    uint8_t* mymv = &mv_lds[w][q][0];

    const double NEG = -1e300;
    double Dp = NEG, Dp2 = NEG;
    float4 cur4 = {0, 0, 0, 0};
    float4 nxt4 = row4[0];

    for (int t = 0; t < 143; ++t) {
        int j = t - r;
        bool act = (j >= 0) & (j < 128);
        if (act & ((j & 3) == 0)) {
            cur4 = nxt4;
            if (j + 4 < 128) nxt4 = row4[(j >> 2) + 1];
        }
        int e = j & 3;
        float sv = (e == 0) ? cur4.x : (e == 1) ? cur4.y : (e == 2) ? cur4.z : cur4.w;
        double up = __shfl_up(Dp, 1);
        double dg = __shfl_up(Dp2, 1);
        double lf = Dp;
        if (r == 0) up = NEG;
        if (j == 0) {
            lf = NEG;
            dg = (r == 0) ? 0.0 : NEG;
        } else if (r == 0) {
            dg = NEG;
        }
        // argmax(up,left,diag), first-max priority (matches np.argmax)
        int m = (up >= lf && up >= dg) ? 0 : ((lf >= dg) ? 1 : 2);
        double Dc = fmax(up, fmax(lf, dg)) + (double)sv;
        if (act) mymv[j * 16 + r] = (uint8_t)m;
        Dp2 = Dp;
        Dp = Dc;
    }
    __syncthreads();

    // backtrack: 4 leader lanes per wave walk their problem's move matrix
    if (r == 0) {
        int i = 16, jj = 128, hic = 127;
        for (int it = 0; it < 160; ++it) {
            if (i <= 0) break;
            int m = mymv[(jj - 1) * 16 + (i - 1)];
            if (m == 1) { --jj; continue; }      // left: stay in row
            bounds[w][q][i - 1] = (jj - 1) | (hic << 8);
            if (m == 2) --jj;                    // diag
            --i;                                 // up or diag
            hic = jj - 1;
        }
    }
    __syncthreads();

    // write masks: 4 problems * 2048 floats = 2048 float4 per wave, coalesced
    #pragma unroll 4
    for (int it = 0; it < 32; ++it) {
        int flat = it * 64 + lane;      // float4 index within wave's 4 problems
        int q2 = flat >> 9;             // 512 float4 per problem
        int rem = flat & 511;
        int ii = rem >> 5;              // 32 float4 per row
        int c4 = rem & 31;
        int b = bounds[w][q2][ii];
        int lo = b & 0xff, hi = (b >> 8) & 0xff;
        int j0 = c4 * 4;
        float4 v;
        v.x = (j0 + 0 >= lo && j0 + 0 <= hi) ? 1.f : 0.f;
        v.y = (j0 + 1 >= lo && j0 + 1 <= hi) ? 1.f : 0.f;
        v.z = (j0 + 2 >= lo && j0 + 2 <= hi) ? 1.f : 0.f;
        v.w = (j0 + 3 >= lo && j0 + 3 <= hi) ? 1.f : 0.f;
        float* tb = buf + (size_t)(pbase + q2) * 2048;
        *(float4*)(tb + ii * 128 + j0) = v;
    }
}

extern "C" void kernel_launch(void* const* d_in, const int* in_sizes, int n_in,
                              void* d_out, int out_size, void* d_ws, size_t ws_size,
                              hipStream_t stream)
{
    const float* c_feats = (const float*)d_in[0];
    const float* f_feats = (const float*)d_in[1];
    float* out = (float*)d_out;

    _Float16* Ah = (_Float16*)d_ws;
    _Float16* Al = Ah + (size_t)M_TOT * K_TOT;
    _Float16* Bh = Al + (size_t)M_TOT * K_TOT;
    _Float16* Bl = Bh + (size_t)N_TOT * K_TOT;
    float* normf = (float*)(Bl + (size_t)N_TOT * K_TOT);

    norm_split_kernel<<<4608, 256, 0, stream>>>(c_feats, f_feats, Ah, Al, Bh, Bl, normf);
    dim3 g(N_TOT / 128, M_TOT / 128);
    mfma_gemm_kernel<<<g, 256, 0, stream>>>(Ah, Al, Bh, Bl, normf, out);
    dtw_kernel<<<1024, 256, 0, stream>>>(out);
}